// Round 9
// baseline (251.390 us; speedup 1.0000x reference)
//
#include <hip/hip_runtime.h>
#include <hip/hip_bf16.h>
#include <hip/hip_fp16.h>

// CRF NLL, B=256, T=1024, L=64. Linear-domain recursion, fp16-pair dot2 matvec,
// state broadcast via LDS same-address ds_read_b128 (HW broadcast). ONE WAVE
// runs BOTH the fwd chain (t=1..h) and bwd chain (t=sl..h+1) of its batch,
// interleaved so each chain's VALU work (32 dots + head) fills the other
// chain's LDS round-trip latency (the R8 wall). Renorm is exact pow-2 with the
// scale computed from the PREVIOUS step's lane-0 exponent (lag-1, off the
// critical path; packed values stay < 2^10 << fp16 max). alpha_h/beta_h meet
// in-wave: Z = sum_j alpha_j beta_j. Gold path = role-1 waves.

typedef _Float16 h2 __attribute__((ext_vector_type(2)));
#define B2U(x) __builtin_bit_cast(unsigned, x)
#define U2H(x) __builtin_bit_cast(h2, x)
#define L2E 1.44269504088896340736f
#define LN2 0.69314718055994530942f
#define EXPE(p) __builtin_amdgcn_exp2f((p) * L2E)

#define W_ALL(M) M(0) M(1) M(2) M(3) M(4) M(5) M(6) M(7) M(8) M(9) M(10) M(11) \
 M(12) M(13) M(14) M(15) M(16) M(17) M(18) M(19) M(20) M(21) M(22) M(23) M(24) \
 M(25) M(26) M(27) M(28) M(29) M(30) M(31)

#define DECLWF(q) unsigned WF##q;
#define DECLWB(q) unsigned WB##q;
#define LOADWF(q) WF##q = B2U(__builtin_amdgcn_cvt_pkrtz(EXPE(tcol[(2*(q))*66]), EXPE(tcol[(2*(q)+1)*66])));
#define LOADWB(q) WB##q = B2U(__builtin_amdgcn_cvt_pkrtz(EXPE(trow[2*(q)]), EXPE(trow[2*(q)+1])));
#define PINWF(q)  asm volatile("" : "+v"(WF##q));
#define PINWB(q)  asm volatile("" : "+v"(WB##q));

#if __has_builtin(__builtin_amdgcn_fdot2)
#define DOTW(u, W, acc) acc = __builtin_amdgcn_fdot2(U2H(u), U2H(W), acc, false);
#else
#define DOTW(u, W, acc) { h2 _u = U2H(u), _w = U2H(W); \
    acc = fmaf((float)_u[0], (float)_w[0], fmaf((float)_u[1], (float)_w[1], acc)); }
#endif
// one b128 quad -> 4 dots
#define D4(v, Wa, Wb, Wc, Wd, A0, A1, A2, A3) \
    DOTW(v.x, Wa, A0) DOTW(v.y, Wb, A1) DOTW(v.z, Wc, A2) DOTW(v.w, Wd, A3)

#define DOTSF \
    D4(f0, WF0,WF1,WF2,WF3,     s0,s1,s2,s3) D4(f1, WF4,WF5,WF6,WF7,     s0,s1,s2,s3) \
    D4(f2, WF8,WF9,WF10,WF11,   s0,s1,s2,s3) D4(f3, WF12,WF13,WF14,WF15, s0,s1,s2,s3) \
    D4(f4, WF16,WF17,WF18,WF19, s0,s1,s2,s3) D4(f5, WF20,WF21,WF22,WF23, s0,s1,s2,s3) \
    D4(f6, WF24,WF25,WF26,WF27, s0,s1,s2,s3) D4(f7, WF28,WF29,WF30,WF31, s0,s1,s2,s3)
#define DOTSB \
    D4(g0, WB0,WB1,WB2,WB3,     t0,t1,t2,t3) D4(g1, WB4,WB5,WB6,WB7,     t0,t1,t2,t3) \
    D4(g2, WB8,WB9,WB10,WB11,   t0,t1,t2,t3) D4(g3, WB12,WB13,WB14,WB15, t0,t1,t2,t3) \
    D4(g4, WB16,WB17,WB18,WB19, t0,t1,t2,t3) D4(g5, WB20,WB21,WB22,WB23, t0,t1,t2,t3) \
    D4(g6, WB24,WB25,WB26,WB27, t0,t1,t2,t3) D4(g7, WB28,WB29,WB30,WB31, t0,t1,t2,t3)

#define ROWC(i) pb[(((i) < 0) ? 0 : (((i) > 1023) ? 1023 : (i))) * 64]

// quad_perm [1,0,3,2] pair swap; full-rate VALU DPP.
#define DPPSWAP(x) __uint_as_float((unsigned)__builtin_amdgcn_mov_dpp( \
    (int)__float_as_uint(x), 0xB1, 0xF, 0xF, true))

// k/sc from lane-0 exponent of v (bias: lane0 -> 2^-5)
#define KSC(v, k, sc) { \
    unsigned ab = (unsigned)__builtin_amdgcn_readfirstlane((int)__float_as_uint(v)); \
    k = (int)((ab >> 23) & 255u) - 122; \
    sc = __uint_as_float((unsigned)(127 - (k)) << 23); }

// Interleaved super-step: fwd (emission EF after matvec) + bwd (EB before).
#define STEP2L(EF, EB) { \
    float xF = aF * scF;          KF += kF; \
    float xoF = DPPSWAP(xF); \
    shF[saddr] = B2U(__builtin_amdgcn_cvt_pkrtz(xF, xoF)); \
    float xB = (aB * scB) * (EB); KB += kB; \
    float xoB = DPPSWAP(xB); \
    shB[saddr] = B2U(__builtin_amdgcn_cvt_pkrtz(xB, xoB)); \
    uint4 f0 = shFv[0], f1 = shFv[1], f2 = shFv[2], f3 = shFv[3], \
          f4 = shFv[4], f5 = shFv[5], f6 = shFv[6], f7 = shFv[7]; \
    uint4 g0 = shBv[0], g1 = shBv[1], g2 = shBv[2], g3 = shBv[3], \
          g4 = shBv[4], g5 = shBv[5], g6 = shBv[6], g7 = shBv[7]; \
    float s0 = 0.f, s1 = 0.f, s2 = 0.f, s3 = 0.f; \
    DOTSF \
    aF = ((s0 + s1) + (s2 + s3)) * (EF); \
    KSC(aF, kF, scF) \
    float t0 = 0.f, t1 = 0.f, t2 = 0.f, t3 = 0.f; \
    DOTSB \
    aB = (t0 + t1) + (t2 + t3); \
    KSC(aB, kB, scB) }

// Lone bwd step (for the +1-length bwd tail). No trailing k update needed.
#define STEPB1L(EB) { \
    float xB = (aB * scB) * (EB); KB += kB; \
    float xoB = DPPSWAP(xB); \
    shB[saddr] = B2U(__builtin_amdgcn_cvt_pkrtz(xB, xoB)); \
    uint4 g0 = shBv[0], g1 = shBv[1], g2 = shBv[2], g3 = shBv[3], \
          g4 = shBv[4], g5 = shBv[5], g6 = shBv[6], g7 = shBv[7]; \
    float t0 = 0.f, t1 = 0.f, t2 = 0.f, t3 = 0.f; \
    DOTSB \
    aB = (t0 + t1) + (t2 + t3); }

__global__ __launch_bounds__(64) __attribute__((amdgpu_waves_per_eu(1, 1)))
void crf_kernel(const float* __restrict__ pred,
                const float* __restrict__ trans,
                const int*   __restrict__ ref,
                const int*   __restrict__ seqlen,
                float* __restrict__ out)
{
    __shared__ __align__(16) unsigned shF[64];
    __shared__ __align__(16) unsigned shB[64];
    const int role = blockIdx.x >> 8;
    const int b    = blockIdx.x & 255;
    const int lane = threadIdx.x;
    const int sl   = seqlen[b];
    const int h    = (sl + 1) >> 1;

    if (role == 1) {
        // ---- gold-path score ----
        const int*   rb = ref  + b * 1024;
        const float* pg = pred + (size_t)b * 65536;
        float acc = 0.f;
        for (int t = lane; t <= sl; t += 64) {
            int from = (t == 0) ? 64 : rb[t - 1];
            int cur  = (t < sl) ? rb[t] : 65;
            acc += trans[from * 66 + cur];
            if (t < sl) acc += pg[t * 64 + cur];
        }
        #pragma unroll
        for (int off = 32; off; off >>= 1) acc += __shfl_xor(acc, off, 64);
        if (lane == 0) atomicAdd(out, -acc);
        return;
    }

    // ---- paired fwd+bwd chains of batch b in one wave ----
    const float* pb   = pred + (size_t)b * 65536 + lane;
    const float* tcol = trans + lane;        // fwd table: V[i][lane]
    const float* trow = trans + lane * 66;   // bwd table: V[lane][i]
    const uint4* shFv = (const uint4*)shF;
    const uint4* shBv = (const uint4*)shB;
    // even lane e -> slot e/2 (read by the dots); odd lanes park in 32..63
    const int saddr = (lane >> 1) + ((lane & 1) << 5);

    W_ALL(DECLWF) W_ALL(DECLWB)
    W_ALL(LOADWF) W_ALL(LOADWB)
    W_ALL(PINWF)  W_ALL(PINWB)

    float aF = EXPE(pb[0] + trans[64 * 66 + lane]);
    float aB = EXPE(trow[65]);
    int KF = 0, KB = 0, kF, kB;
    float scF, scB;
    KSC(aF, kF, scF)
    KSC(aB, kB, scB)

    const int nF = h - 1;        // fwd steps  (rows 1 .. h-1)
    const int nB = sl - h;       // bwd steps  (rows sl-1 .. h), nB - nF in {0,1}
    int rF = 1, rB = sl - 1;
    int n4 = nF;

    float EF0 = EXPE(ROWC(rF)),     EF1 = EXPE(ROWC(rF + 1)),
          EF2 = EXPE(ROWC(rF + 2)), EF3 = EXPE(ROWC(rF + 3));
    float EB0 = EXPE(ROWC(rB)),     EB1 = EXPE(ROWC(rB - 1)),
          EB2 = EXPE(ROWC(rB - 2)), EB3 = EXPE(ROWC(rB - 3));

    while (n4 >= 4) {
        float FF0 = ROWC(rF + 4), FF1 = ROWC(rF + 5), FF2 = ROWC(rF + 6), FF3 = ROWC(rF + 7);
        float FB0 = ROWC(rB - 4), FB1 = ROWC(rB - 5), FB2 = ROWC(rB - 6), FB3 = ROWC(rB - 7);
        STEP2L(EF0, EB0) STEP2L(EF1, EB1) STEP2L(EF2, EB2) STEP2L(EF3, EB3)
        EF0 = EXPE(FF0); EF1 = EXPE(FF1); EF2 = EXPE(FF2); EF3 = EXPE(FF3);
        EB0 = EXPE(FB0); EB1 = EXPE(FB1); EB2 = EXPE(FB2); EB3 = EXPE(FB3);
        rF += 4; rB -= 4; n4 -= 4;
    }
    if (n4 > 0) { STEP2L(EF0, EB0) }
    if (n4 > 1) { STEP2L(EF1, EB1) }
    if (n4 > 2) { STEP2L(EF2, EB2) }
    if (nB > nF) {
        float EBn = (n4 == 0) ? EB0 : (n4 == 1) ? EB1 : (n4 == 2) ? EB2 : EB3;
        STEPB1L(EBn)
    }

    // in-wave combine: Z = sum_j alpha_h[j] * beta_h[j]
    float z = aF * aB;
    #pragma unroll
    for (int off = 32; off; off >>= 1) z += __shfl_xor(z, off, 64);
    if (lane == 0) {
        float res = LN2 * (__builtin_amdgcn_logf(z) + (float)(KF + KB));
        atomicAdd(out, res);
    }
}

extern "C" void kernel_launch(void* const* d_in, const int* in_sizes, int n_in,
                              void* d_out, int out_size, void* d_ws, size_t ws_size,
                              hipStream_t stream) {
    const float* pred   = (const float*)d_in[0];
    const float* trans  = (const float*)d_in[1];
    const int*   ref    = (const int*)d_in[2];
    const int*   seqlen = (const int*)d_in[3];
    float* out = (float*)d_out;
    hipMemsetAsync(out, 0, sizeof(float), stream);
    crf_kernel<<<512, 64, 0, stream>>>(pred, trans, ref, seqlen, out);
}

// Round 10
// 246.570 us; speedup vs baseline: 1.0195x; 1.0195x over previous
//
#include <hip/hip_runtime.h>
#include <hip/hip_bf16.h>
#include <hip/hip_fp16.h>

// CRF NLL, B=256, T=1024, L=64. Linear-domain recursion, fp16-pair dot2 matvec,
// LDS same-address b128 broadcast. ONE WAVE runs fwd+bwd chains of its batch in
// an explicit half-step-shifted software pipeline:
//   [F-dots][F-head: write+issue f] [B-dots][B-head: write+issue g]
// so each chain's LDS round-trip is covered by the other chain's dot block.
// sched_barrier(0) fences keep the compiler from re-serializing (the R9 failure:
// pressure-driven scheduler sank the 2nd chain's reads below the 1st's dots).
// Exact pow-2 renorm (lane-0 exponent, -5 bias), K accumulated at TAIL via
// pending-k so the final orphaned head doesn't corrupt the ledger.

typedef _Float16 h2 __attribute__((ext_vector_type(2)));
#define B2U(x) __builtin_bit_cast(unsigned, x)
#define U2H(x) __builtin_bit_cast(h2, x)
#define L2E 1.44269504088896340736f
#define LN2 0.69314718055994530942f
#define EXPE(p) __builtin_amdgcn_exp2f((p) * L2E)
#define SBAR __builtin_amdgcn_sched_barrier(0)

#define W_ALL(M) M(0) M(1) M(2) M(3) M(4) M(5) M(6) M(7) M(8) M(9) M(10) M(11) \
 M(12) M(13) M(14) M(15) M(16) M(17) M(18) M(19) M(20) M(21) M(22) M(23) M(24) \
 M(25) M(26) M(27) M(28) M(29) M(30) M(31)

#define DECLWF(q) unsigned WF##q;
#define DECLWB(q) unsigned WB##q;
#define LOADWF(q) WF##q = B2U(__builtin_amdgcn_cvt_pkrtz(EXPE(tcol[(2*(q))*66]), EXPE(tcol[(2*(q)+1)*66])));
#define LOADWB(q) WB##q = B2U(__builtin_amdgcn_cvt_pkrtz(EXPE(trow[2*(q)]), EXPE(trow[2*(q)+1])));
#define PINWF(q)  asm volatile("" : "+v"(WF##q));
#define PINWB(q)  asm volatile("" : "+v"(WB##q));

#if __has_builtin(__builtin_amdgcn_fdot2)
#define DOTW(u, W, acc) acc = __builtin_amdgcn_fdot2(U2H(u), U2H(W), acc, false);
#else
#define DOTW(u, W, acc) { h2 _u = U2H(u), _w = U2H(W); \
    acc = fmaf((float)_u[0], (float)_w[0], fmaf((float)_u[1], (float)_w[1], acc)); }
#endif
#define D4(v, Wa, Wb, Wc, Wd) \
    DOTW(v.x, Wa, a0) DOTW(v.y, Wb, a1) DOTW(v.z, Wc, a2) DOTW(v.w, Wd, a3)

#define FDOTS { float a0=0.f,a1=0.f,a2=0.f,a3=0.f; \
    D4(qf0, WF0,WF1,WF2,WF3)     D4(qf1, WF4,WF5,WF6,WF7) \
    D4(qf2, WF8,WF9,WF10,WF11)   D4(qf3, WF12,WF13,WF14,WF15) \
    D4(qf4, WF16,WF17,WF18,WF19) D4(qf5, WF20,WF21,WF22,WF23) \
    D4(qf6, WF24,WF25,WF26,WF27) D4(qf7, WF28,WF29,WF30,WF31) \
    sF = (a0 + a1) + (a2 + a3); }
#define BDOTS { float a0=0.f,a1=0.f,a2=0.f,a3=0.f; \
    D4(qg0, WB0,WB1,WB2,WB3)     D4(qg1, WB4,WB5,WB6,WB7) \
    D4(qg2, WB8,WB9,WB10,WB11)   D4(qg3, WB12,WB13,WB14,WB15) \
    D4(qg4, WB16,WB17,WB18,WB19) D4(qg5, WB20,WB21,WB22,WB23) \
    D4(qg6, WB24,WB25,WB26,WB27) D4(qg7, WB28,WB29,WB30,WB31) \
    sB = (a0 + a1) + (a2 + a3); }

#define ROWC(i) pb[(((i) < 0) ? 0 : (((i) > 1023) ? 1023 : (i))) * 64]

#define DPPSWAP(x) __uint_as_float((unsigned)__builtin_amdgcn_mov_dpp( \
    (int)__float_as_uint(x), 0xB1, 0xF, 0xF, true))

#define KSCM(v, k, sc) { \
    unsigned _ab = (unsigned)__builtin_amdgcn_readfirstlane((int)__float_as_uint(v)); \
    k = (int)((_ab >> 23) & 255u) - 122; \
    sc = __uint_as_float((unsigned)(127 - (k)) << 23); }

#define FISSUE { float xF = aF * scF; float xoF = DPPSWAP(xF); \
    shF[saddr] = B2U(__builtin_amdgcn_cvt_pkrtz(xF, xoF)); \
    qf0 = shFv[0]; qf1 = shFv[1]; qf2 = shFv[2]; qf3 = shFv[3]; \
    qf4 = shFv[4]; qf5 = shFv[5]; qf6 = shFv[6]; qf7 = shFv[7]; }
#define BISSUE(EBn) { float xB = (aB * scB) * (EBn); float xoB = DPPSWAP(xB); \
    shB[saddr] = B2U(__builtin_amdgcn_cvt_pkrtz(xB, xoB)); \
    qg0 = shBv[0]; qg1 = shBv[1]; qg2 = shBv[2]; qg3 = shBv[3]; \
    qg4 = shBv[4]; qg5 = shBv[5]; qg6 = shBv[6]; qg7 = shBv[7]; }

// One pipelined super-step: completes fwd step j and bwd step j, issues j+1.
#define STEPP(EFn, EBn) { \
    SBAR; \
    float sF; FDOTS \
    aF = sF * EFc; KF += kFp; KSCM(aF, kF, scF) kFp = kF; \
    SBAR; \
    FISSUE \
    SBAR; \
    float sB; BDOTS \
    aB = sB; KB += kBp; KSCM(aB, kB, scB) kBp = kB; \
    SBAR; \
    BISSUE(EBn) \
    EFc = (EFn); }

__global__ __launch_bounds__(64) __attribute__((amdgpu_waves_per_eu(1, 1)))
void crf_kernel(const float* __restrict__ pred,
                const float* __restrict__ trans,
                const int*   __restrict__ ref,
                const int*   __restrict__ seqlen,
                float* __restrict__ out)
{
    __shared__ __align__(16) unsigned shF[64];
    __shared__ __align__(16) unsigned shB[64];
    const int role = blockIdx.x >> 8;
    const int b    = blockIdx.x & 255;
    const int lane = threadIdx.x;
    const int sl   = seqlen[b];
    const int h    = (sl + 1) >> 1;

    if (role == 1) {
        // ---- gold-path score ----
        const int*   rb = ref  + b * 1024;
        const float* pg = pred + (size_t)b * 65536;
        float acc = 0.f;
        for (int t = lane; t <= sl; t += 64) {
            int from = (t == 0) ? 64 : rb[t - 1];
            int cur  = (t < sl) ? rb[t] : 65;
            acc += trans[from * 66 + cur];
            if (t < sl) acc += pg[t * 64 + cur];
        }
        #pragma unroll
        for (int off = 32; off; off >>= 1) acc += __shfl_xor(acc, off, 64);
        if (lane == 0) atomicAdd(out, -acc);
        return;
    }

    // ---- pipelined fwd+bwd chains of batch b in one wave ----
    const float* pb   = pred + (size_t)b * 65536 + lane;
    const float* tcol = trans + lane;        // fwd table: V[i][lane]
    const float* trow = trans + lane * 66;   // bwd table: V[lane][i]
    const uint4* shFv = (const uint4*)shF;
    const uint4* shBv = (const uint4*)shB;
    const int saddr = (lane >> 1) + ((lane & 1) << 5);

    W_ALL(DECLWF) W_ALL(DECLWB)
    W_ALL(LOADWF) W_ALL(LOADWB)
    W_ALL(PINWF)  W_ALL(PINWB)

    uint4 qf0, qf1, qf2, qf3, qf4, qf5, qf6, qf7;
    uint4 qg0, qg1, qg2, qg3, qg4, qg5, qg6, qg7;

    float aF = EXPE(pb[0] + trans[64 * 66 + lane]);
    float aB = EXPE(trow[65]);
    int KF = 0, KB = 0, kF, kB, kFp, kBp;
    float scF, scB;
    KSCM(aF, kF, scF) kFp = kF;
    KSCM(aB, kB, scB) kBp = kB;

    const int nF = h - 1;        // fwd steps: rows 1 .. h-1
    const int nB = sl - h;       // bwd steps: rows sl-1 .. h; nB-nF in {0,1}

    // Preamble: head(0) for both chains.
    FISSUE
    { float EB0v = EXPE(ROWC(sl - 1)); BISSUE(EB0v) }
    float EFc = EXPE(ROWC(1));

    // Rolling raw-row prefetch (4 deep). pF0 = row 2+j at block start.
    int rF = 2, rB = sl - 2, n = nF;
    float pF0 = ROWC(rF),     pF1 = ROWC(rF + 1), pF2 = ROWC(rF + 2), pF3 = ROWC(rF + 3);
    float pB0 = ROWC(rB),     pB1 = ROWC(rB - 1), pB2 = ROWC(rB - 2), pB3 = ROWC(rB - 3);

    while (n >= 4) {
        float FF0 = ROWC(rF + 4), FF1 = ROWC(rF + 5), FF2 = ROWC(rF + 6), FF3 = ROWC(rF + 7);
        float FB0 = ROWC(rB - 4), FB1 = ROWC(rB - 5), FB2 = ROWC(rB - 6), FB3 = ROWC(rB - 7);
        STEPP(EXPE(pF0), EXPE(pB0))
        STEPP(EXPE(pF1), EXPE(pB1))
        STEPP(EXPE(pF2), EXPE(pB2))
        STEPP(EXPE(pF3), EXPE(pB3))
        pF0 = FF0; pF1 = FF1; pF2 = FF2; pF3 = FF3;
        pB0 = FB0; pB1 = FB1; pB2 = FB2; pB3 = FB3;
        rF += 4; rB -= 4; n -= 4;
    }
    if (n > 0) { STEPP(EXPE(pF0), EXPE(pB0)) --n; }
    if (n > 0) { STEPP(EXPE(pF1), EXPE(pB1)) --n; }
    if (n > 0) { STEPP(EXPE(pF2), EXPE(pB2)) }

    if (nB > nF) {   // one extra bwd step; its head was issued in the last STEPP
        SBAR;
        float sB; BDOTS
        aB = sB; KB += kBp;
    }

    // in-wave combine: Z = sum_j alpha_h[j] * beta_h[j]
    float z = aF * aB;
    #pragma unroll
    for (int off = 32; off; off >>= 1) z += __shfl_xor(z, off, 64);
    if (lane == 0) {
        float res = LN2 * (__builtin_amdgcn_logf(z) + (float)(KF + KB));
        atomicAdd(out, res);
    }
}

extern "C" void kernel_launch(void* const* d_in, const int* in_sizes, int n_in,
                              void* d_out, int out_size, void* d_ws, size_t ws_size,
                              hipStream_t stream) {
    const float* pred   = (const float*)d_in[0];
    const float* trans  = (const float*)d_in[1];
    const int*   ref    = (const int*)d_in[2];
    const int*   seqlen = (const int*)d_in[3];
    float* out = (float*)d_out;
    hipMemsetAsync(out, 0, sizeof(float), stream);
    crf_kernel<<<512, 64, 0, stream>>>(pred, trans, ref, seqlen, out);
}